// Round 4
// baseline (6423.537 us; speedup 1.0000x reference)
//
#include <hip/hip_runtime.h>
#include <cstdint>

#define NNODES 20000
#define NEDGES 320000
#define ETOT   340000   // NEDGES + NNODES self loops
#define TSTEPS 10
#define BCLF   4096
#define EMB    128
#define HC     512      // HEADS * EMB
#define NEG_SLOPE 0.2f

#define RNG    1024     // dst nodes per CSR range block
#define NRANGE 20       // ceil(20000/1024)
#define CAP    24576    // LDS staging ints per range (max range load ~17.5k)

typedef _Float16 half_t;
typedef __attribute__((ext_vector_type(8))) _Float16 half8;
typedef __attribute__((ext_vector_type(4))) float floatx4;

// ---------------- conversions ----------------
__global__ void cvt_h_kernel(const float* __restrict__ in, half_t* __restrict__ out, long n4) {
    long i = (long)blockIdx.x * 256 + threadIdx.x;
    if (i >= n4) return;
    float4 v = *(const float4*)&in[i * 4];
    half_t o[4] = {(half_t)v.x, (half_t)v.y, (half_t)v.z, (half_t)v.w};
    *(unsigned long long*)&out[i * 4] = *(unsigned long long*)o;
}

__global__ void cvt_split_kernel(const float* __restrict__ in,
                                 half_t* __restrict__ hi, half_t* __restrict__ lo, long n4) {
    long i = (long)blockIdx.x * 256 + threadIdx.x;
    if (i >= n4) return;
    float4 v = *(const float4*)&in[i * 4];
    half_t h[4], l[4];
    h[0] = (half_t)v.x; l[0] = (half_t)(v.x - (float)h[0]);
    h[1] = (half_t)v.y; l[1] = (half_t)(v.y - (float)h[1]);
    h[2] = (half_t)v.z; l[2] = (half_t)(v.z - (float)h[2]);
    h[3] = (half_t)v.w; l[3] = (half_t)(v.w - (float)h[3]);
    *(unsigned long long*)&hi[i * 4] = *(unsigned long long*)h;
    *(unsigned long long*)&lo[i * 4] = *(unsigned long long*)l;
}

// ---------------- CSR build: range-partitioned, LDS-staged ----------------
__global__ __launch_bounds__(256) void rc_count(const int* __restrict__ edges,
                                                int* __restrict__ locoff, int* __restrict__ rtot) {
    int r = blockIdx.x, g = blockIdx.y;
    int tid = threadIdx.x;
    __shared__ int cnt[RNG];
    __shared__ int sc[256];
    int base = r * RNG;
    int lim = NNODES - base; if (lim > RNG) lim = RNG;
    for (int i = tid; i < RNG; i += 256) cnt[i] = 0;
    __syncthreads();
    const int* dste = edges + (g * 2 + 1) * NEDGES;
    for (int e = tid; e < ETOT; e += 256) {
        int d = (e < NEDGES) ? dste[e] : (e - NEDGES);
        int rel = d - base;
        if ((unsigned)rel < (unsigned)lim) atomicAdd(&cnt[rel], 1);
    }
    __syncthreads();
    int c0 = cnt[tid * 4], c1 = cnt[tid * 4 + 1], c2 = cnt[tid * 4 + 2], c3 = cnt[tid * 4 + 3];
    int s = c0 + c1 + c2 + c3;
    sc[tid] = s;
    __syncthreads();
    for (int off = 1; off < 256; off <<= 1) {
        int tv = (tid >= off) ? sc[tid - off] : 0;
        __syncthreads();
        sc[tid] += tv;
        __syncthreads();
    }
    int ex = sc[tid] - s;
    cnt[tid * 4] = ex; cnt[tid * 4 + 1] = ex + c0;
    cnt[tid * 4 + 2] = ex + c0 + c1; cnt[tid * 4 + 3] = ex + c0 + c1 + c2;
    __syncthreads();
    for (int i = tid; i < RNG; i += 256)
        locoff[((long)g * NRANGE + r) * RNG + i] = cnt[i];
    if (tid == 0) rtot[g * NRANGE + r] = sc[255];
}

__global__ void rc_base(const int* __restrict__ rtot, int* __restrict__ rbase) {
    if (threadIdx.x == 0 && blockIdx.x == 0) {
        for (int g = 0; g < TSTEPS; g++) {
            int acc = 0;
            for (int r = 0; r < NRANGE; r++) {
                rbase[g * NRANGE + r] = acc;
                acc += rtot[g * NRANGE + r];
            }
        }
    }
}

__global__ __launch_bounds__(256) void rc_fill(const int* __restrict__ edges,
                                               const int* __restrict__ locoff,
                                               const int* __restrict__ rtot,
                                               const int* __restrict__ rbase,
                                               int* __restrict__ rowptr, int* __restrict__ csr_src) {
    int r = blockIdx.x, g = blockIdx.y;
    int tid = threadIdx.x;
    __shared__ int cur[RNG];
    __shared__ int stage[CAP];
    int base = r * RNG;
    int lim = NNODES - base; if (lim > RNG) lim = RNG;
    int rb = rbase[g * NRANGE + r];
    for (int i = tid; i < RNG; i += 256) {
        int lo = locoff[((long)g * NRANGE + r) * RNG + i];
        cur[i] = lo;
        if (i < lim) rowptr[g * (NNODES + 1) + base + i] = rb + lo;
    }
    if (tid == 0 && r == NRANGE - 1) rowptr[g * (NNODES + 1) + NNODES] = ETOT;
    __syncthreads();
    const int* srce = edges + (g * 2) * NEDGES;
    const int* dste = edges + (g * 2 + 1) * NEDGES;
    for (int e = tid; e < ETOT; e += 256) {
        int s, d;
        if (e < NEDGES) { s = srce[e]; d = dste[e]; }
        else            { s = e - NEDGES; d = s; }
        int rel = d - base;
        if ((unsigned)rel < (unsigned)lim) {
            int p = atomicAdd(&cur[rel], 1);
            stage[p] = s;
        }
    }
    __syncthreads();
    int tot = rtot[g * NRANGE + r];
    for (int i = tid; i < tot; i += 256)
        csr_src[(long)g * ETOT + rb + i] = stage[i];
}

// ---------------- precompute was/wad: was[l][z][h][k] = sum_c W[h*128+c][k]*as[h][c] ----------------
__global__ void prep_was_kernel(const float* __restrict__ W1, const float* __restrict__ W2,
                                const float* __restrict__ as1, const float* __restrict__ as2,
                                const float* __restrict__ ad1, const float* __restrict__ ad2,
                                float* __restrict__ was, float* __restrict__ wad) {
    int b = blockIdx.x;            // l*8 + z*4 + h
    int l = b >> 3, z = (b >> 2) & 1, h = b & 3;
    int k = threadIdx.x;           // 128
    const float* W  = z ? W2 : W1;
    const float* av = z ? as2 : as1;
    const float* dv = z ? ad2 : ad1;
    float s = 0.f, d = 0.f;
    for (int c = 0; c < 128; c++) {
        float w = W[(long)l * HC * EMB + (h * 128 + c) * 128 + k];
        s = fmaf(w, av[(l * 4 + h) * 128 + c], s);
        d = fmaf(w, dv[(l * 4 + h) * 128 + c], d);
    }
    long idx = ((l * 2 + z) * 4 + h) * 128 + k;
    was[idx] = s;
    wad[idx] = d;
}

// ---------------- layer-0 scores for ALL timesteps, from fp32 emb ----------------
__global__ __launch_bounds__(256) void scores0_all_kernel(
    const float* __restrict__ emb,
    const float* __restrict__ was0, const float* __restrict__ wad0,   // [z][4][128]
    float* __restrict__ s0src, float* __restrict__ s0dst) {           // [t][z][N][4]
    int z = blockIdx.y;
    int t = blockIdx.x / 5000;
    int nb = blockIdx.x % 5000;
    int n = nb * 4 + (threadIdx.x >> 6);
    int lane = threadIdx.x & 63;
    const float* xr = emb + ((long)t * NNODES + n) * 128;
    float x0 = xr[lane], x1 = xr[64 + lane];
    const float* wz = was0 + z * 512;
    const float* dz = wad0 + z * 512;
    float ps[4], pd[4];
#pragma unroll
    for (int h = 0; h < 4; h++) {
        ps[h] = x0 * wz[h * 128 + lane] + x1 * wz[h * 128 + 64 + lane];
        pd[h] = x0 * dz[h * 128 + lane] + x1 * dz[h * 128 + 64 + lane];
    }
    for (int off = 32; off; off >>= 1) {
#pragma unroll
        for (int h = 0; h < 4; h++) {
            ps[h] += __shfl_down(ps[h], off);
            pd[h] += __shfl_down(pd[h], off);
        }
    }
    if (lane == 0) {
        long idx = (((long)t * 2 + z) * NNODES + n) * 4;
#pragma unroll
        for (int h = 0; h < 4; h++) {
            s0src[idx + h] = ps[h];
            s0dst[idx + h] = pd[h];
        }
    }
}

// ---------------- A-split fp16 MFMA GEMM: C = op(A @ B^T + bias) ----------------
// A = Ah + Al (hi/lo fp16 pair), B single fp16 [N,K]. 2 MFMAs per product term.
// Tile 128x128, BK=32, 4 waves, 4x4 of 16x16x32 MFMAs per wave. blockIdx.z = branch.
template <bool RELU, bool BIAS, bool F32OUT>
__global__ __launch_bounds__(256) void gemm_as(
    const half_t* __restrict__ A0h, const half_t* __restrict__ A0l,
    const half_t* __restrict__ A1h, const half_t* __restrict__ A1l,
    const half_t* __restrict__ B0, const half_t* __restrict__ B1,
    const float* __restrict__ bias0, const float* __restrict__ bias1,
    half_t* __restrict__ Ch, float* __restrict__ Cf,
    long cStride, int M, int N, int K) {
    const int z = blockIdx.z;
    const half_t* __restrict__ Ah = z ? A1h : A0h;
    const half_t* __restrict__ Al = z ? A1l : A0l;
    const half_t* __restrict__ B  = z ? B1 : B0;
    const float* __restrict__ bias = z ? bias1 : bias0;

    __shared__ half_t Ash[4 * 128 * 8];   // 8 KB
    __shared__ half_t Asl[4 * 128 * 8];
    __shared__ half_t Bs[4 * 128 * 8];

    const int tid = threadIdx.x;
    const int row0 = blockIdx.x * 128;
    const int col0 = blockIdx.y * 128;
    const int wave = tid >> 6;
    const int lane = tid & 63;
    const int wm = (wave >> 1) * 64;
    const int wn = (wave & 1) * 64;
    const int chunk = lane >> 4;
    const int l16 = lane & 15;

    floatx4 acc[4][4];
#pragma unroll
    for (int i = 0; i < 4; i++)
#pragma unroll
        for (int j = 0; j < 4; j++) acc[i][j] = (floatx4)0.0f;

    for (int k0 = 0; k0 < K; k0 += 32) {
        __syncthreads();
#pragma unroll
        for (int p = 0; p < 2; p++) {
            int idx = p * 256 + tid;
            int r = idx >> 2, kc = idx & 3;
            int arow = row0 + r;
            half8 vah, val;
            if (arow < M) {
                vah = *(const half8*)&Ah[(long)arow * K + k0 + kc * 8];
                val = *(const half8*)&Al[(long)arow * K + k0 + kc * 8];
            } else {
#pragma unroll
                for (int q = 0; q < 8; q++) { vah[q] = (half_t)0.f; val[q] = (half_t)0.f; }
            }
            *(half8*)&Ash[(kc * 128 + r) * 8] = vah;
            *(half8*)&Asl[(kc * 128 + r) * 8] = val;
            *(half8*)&Bs[(kc * 128 + r) * 8] = *(const half8*)&B[(long)(col0 + r) * K + k0 + kc * 8];
        }
        __syncthreads();
        half8 afh[4], afl[4], bf[4];
#pragma unroll
        for (int mi = 0; mi < 4; mi++) {
            int o = (chunk * 128 + wm + mi * 16 + l16) * 8;
            afh[mi] = *(const half8*)&Ash[o];
            afl[mi] = *(const half8*)&Asl[o];
        }
#pragma unroll
        for (int ni = 0; ni < 4; ni++)
            bf[ni] = *(const half8*)&Bs[(chunk * 128 + wn + ni * 16 + l16) * 8];
#pragma unroll
        for (int mi = 0; mi < 4; mi++)
#pragma unroll
            for (int ni = 0; ni < 4; ni++) {
                acc[mi][ni] = __builtin_amdgcn_mfma_f32_16x16x32_f16(
                    afh[mi], bf[ni], acc[mi][ni], 0, 0, 0);
                acc[mi][ni] = __builtin_amdgcn_mfma_f32_16x16x32_f16(
                    afl[mi], bf[ni], acc[mi][ni], 0, 0, 0);
            }
    }

    const int r4 = (lane >> 4) * 4;
#pragma unroll
    for (int mi = 0; mi < 4; mi++) {
#pragma unroll
        for (int reg = 0; reg < 4; reg++) {
            int row = row0 + wm + mi * 16 + r4 + reg;
            if (row >= M) continue;
#pragma unroll
            for (int ni = 0; ni < 4; ni++) {
                int col = col0 + wn + ni * 16 + l16;
                float v = acc[mi][ni][reg];
                if (BIAS) v += bias[col];
                if (RELU) v = fmaxf(v, 0.f);
                long o = (long)z * cStride + (long)row * N + col;
                if (F32OUT) Cf[o] = v;
                else        Ch[o] = (half_t)v;
            }
        }
    }
}

// ---------------- fused: CSR aggregation -> LDS -> MFMA lin -> X' split (+ next scores) ----------------
// Block = 16 dst nodes, 4 waves. Stage 1: wave w gathers dst w*4..w*4+3 (lane = 8 channels).
// Stage 2: wave w computes X'[16, w*32..w*32+32) via 16x16x32 fp16 MFMA, B-frags from global lW.
template <bool WITH_SCORES>
__global__ __launch_bounds__(256) void agg_fused(
    const half_t* __restrict__ H,
    const float* __restrict__ s_src, const float* __restrict__ s_dst,   // [z][N][4]
    const int* __restrict__ rowptr, const int* __restrict__ csr_src,
    const float* __restrict__ gb0, const float* __restrict__ gb1,       // gat bias [512]
    const half_t* __restrict__ lw0, const half_t* __restrict__ lw1,     // lin W fp16 [128][512]
    const float* __restrict__ lb0, const float* __restrict__ lb1,       // lin bias [128]
    half_t* __restrict__ Xh, half_t* __restrict__ Xl,                   // out [z][N][128]
    const float* __restrict__ wasn, const float* __restrict__ wadn,     // next layer [z][4][128]
    float* __restrict__ so_src, float* __restrict__ so_dst,             // out scores [z][N][4]
    int g) {
    __shared__ half_t Ahs[16][520];
    __shared__ half_t Als[16][520];
    __shared__ float  Xs[16][132];
    int z = blockIdx.y;
    int n0 = blockIdx.x * 16;
    int tid = threadIdx.x;
    int wave = tid >> 6, lane = tid & 63;
    int head = lane >> 4, l16 = lane & 15, chunk = lane >> 4;
    const int* rp = rowptr + g * (NNODES + 1);
    const int* cs = csr_src + (long)g * ETOT;
    const float* gb = z ? gb1 : gb0;

    // ---- stage 1: gather + softmax-normalize + bias -> LDS (split fp16) ----
#pragma unroll 1
    for (int i = 0; i < 4; i++) {
        int dl = wave * 4 + i;
        int n = n0 + dl;
        int beg = rp[n], end = rp[n + 1];
        float sd = s_dst[((long)z * NNODES + n) * 4 + head];
        float acc[8];
#pragma unroll
        for (int c = 0; c < 8; c++) acc[c] = 0.f;
        float den = 0.f;
        for (int j = beg; j < end; j++) {
            int src = cs[j];
            float ss = s_src[((long)z * NNODES + src) * 4 + head];
            float L = ss + sd;
            L = (L >= 0.f) ? L : NEG_SLOPE * L;
            float w = __expf(L);
            den += w;
            half8 h8 = *(const half8*)&H[((long)z * NNODES + src) * HC + lane * 8];
#pragma unroll
            for (int c = 0; c < 8; c++) acc[c] = fmaf(w, (float)h8[c], acc[c]);
        }
        float inv = 1.0f / den;
#pragma unroll
        for (int c = 0; c < 8; c++) {
            float v = acc[c] * inv + gb[lane * 8 + c];
            half_t hi = (half_t)v;
            Ahs[dl][lane * 8 + c] = hi;
            Als[dl][lane * 8 + c] = (half_t)(v - (float)hi);
        }
    }
    __syncthreads();

    // ---- stage 2: X'[16 x 32cols] = relu(OUT @ lW^T + lb), MFMA ----
    const half_t* lw = z ? lw1 : lw0;
    const float* lb = z ? lb1 : lb0;
    floatx4 acc2[2];
    acc2[0] = (floatx4)0.0f;
    acc2[1] = (floatx4)0.0f;
#pragma unroll
    for (int kk = 0; kk < 16; kk++) {
        int ko = kk * 32 + chunk * 8;
        half8 a_h = *(const half8*)&Ahs[l16][ko];
        half8 a_l = *(const half8*)&Als[l16][ko];
#pragma unroll
        for (int ni = 0; ni < 2; ni++) {
            int col = wave * 32 + ni * 16 + l16;
            half8 b = *(const half8*)&lw[(long)col * 512 + ko];
            acc2[ni] = __builtin_amdgcn_mfma_f32_16x16x32_f16(a_h, b, acc2[ni], 0, 0, 0);
            acc2[ni] = __builtin_amdgcn_mfma_f32_16x16x32_f16(a_l, b, acc2[ni], 0, 0, 0);
        }
    }
    int r4 = (lane >> 4) * 4;
#pragma unroll
    for (int ni = 0; ni < 2; ni++) {
        int col = wave * 32 + ni * 16 + l16;
        float lbv = lb[col];
#pragma unroll
        for (int reg = 0; reg < 4; reg++) {
            int rl = r4 + reg;
            int row = n0 + rl;
            float v = fmaxf(acc2[ni][reg] + lbv, 0.f);
            half_t hi = (half_t)v;
            long o = ((long)z * NNODES + row) * 128 + col;
            Xh[o] = hi;
            Xl[o] = (half_t)(v - (float)hi);
            if (WITH_SCORES) Xs[rl][col] = v;
        }
    }

    if (WITH_SCORES) {
        __syncthreads();
        const float* wz = wasn + z * 512;
        const float* dz = wadn + z * 512;
#pragma unroll 1
        for (int i = 0; i < 4; i++) {
            int rl = wave * 4 + i;
            int n = n0 + rl;
            float x0 = Xs[rl][lane], x1 = Xs[rl][64 + lane];
            float ps[4], pd[4];
#pragma unroll
            for (int h = 0; h < 4; h++) {
                ps[h] = x0 * wz[h * 128 + lane] + x1 * wz[h * 128 + 64 + lane];
                pd[h] = x0 * dz[h * 128 + lane] + x1 * dz[h * 128 + 64 + lane];
            }
            for (int off = 32; off; off >>= 1) {
#pragma unroll
                for (int h = 0; h < 4; h++) {
                    ps[h] += __shfl_down(ps[h], off);
                    pd[h] += __shfl_down(pd[h], off);
                }
            }
            if (lane == 0) {
                long idx = ((long)z * NNODES + n) * 4;
#pragma unroll
                for (int h = 0; h < 4; h++) {
                    so_src[idx + h] = ps[h];
                    so_dst[idx + h] = pd[h];
                }
            }
        }
    }
}

// ---------------- gather clf_nodes into flat MLP input (reversed timesteps) ----------------
__global__ void gather_kernel(const half_t* __restrict__ Xh, const half_t* __restrict__ Xl,
                              const int* __restrict__ clf,
                              half_t* __restrict__ flath, half_t* __restrict__ flatl, int t) {
    int b = blockIdx.x;
    int z = blockIdx.y;
    int j = threadIdx.x;  // 64 dwords = 128 halves
    int node = clf[b];
    long dst = (long)b * (TSTEPS * 2 * EMB) + (TSTEPS - 1 - t) * (2 * EMB) + z * EMB;
    long src = ((long)z * NNODES + node) * EMB;
    ((unsigned int*)&flath[dst])[j] = ((const unsigned int*)&Xh[src])[j];
    ((unsigned int*)&flatl[dst])[j] = ((const unsigned int*)&Xl[src])[j];
}

// ---------------- fc2: [B,128] @ [2,128]^T + bias, relu, fp32 out ----------------
__global__ void fc2_kernel(const float* __restrict__ h1, const float* __restrict__ W,
                           const float* __restrict__ bias, float* __restrict__ out) {
    int row = blockIdx.x;
    int lane = threadIdx.x;  // 64
    float x0 = h1[(long)row * 128 + lane];
    float x1 = h1[(long)row * 128 + 64 + lane];
    float p0 = x0 * W[lane] + x1 * W[64 + lane];
    float p1 = x0 * W[128 + lane] + x1 * W[192 + lane];
    for (int off = 32; off; off >>= 1) {
        p0 += __shfl_down(p0, off);
        p1 += __shfl_down(p1, off);
    }
    if (lane == 0) {
        out[row * 2 + 0] = fmaxf(p0 + bias[0], 0.f);
        out[row * 2 + 1] = fmaxf(p1 + bias[1], 0.f);
    }
}

extern "C" void kernel_launch(void* const* d_in, const int* in_sizes, int n_in,
                              void* d_out, int out_size, void* d_ws, size_t ws_size,
                              hipStream_t stream) {
    const float* emb     = (const float*)d_in[0];
    const int*   edges   = (const int*)d_in[1];
    const int*   clf     = (const int*)d_in[5];
    const float* gat_W1  = (const float*)d_in[6];
    const float* gat_as1 = (const float*)d_in[7];
    const float* gat_ad1 = (const float*)d_in[8];
    const float* gat_b1  = (const float*)d_in[9];
    const float* lin_W1  = (const float*)d_in[10];
    const float* lin_b1  = (const float*)d_in[11];
    const float* gat_W2  = (const float*)d_in[12];
    const float* gat_as2 = (const float*)d_in[13];
    const float* gat_ad2 = (const float*)d_in[14];
    const float* gat_b2  = (const float*)d_in[15];
    const float* lin_W2  = (const float*)d_in[16];
    const float* lin_b2  = (const float*)d_in[17];
    const float* fc1_W   = (const float*)d_in[18];
    const float* fc1_b   = (const float*)d_in[19];
    const float* fc2_W   = (const float*)d_in[20];
    const float* fc2_b   = (const float*)d_in[21];
    float* out = (float*)d_out;

    char* ws = (char*)d_ws;
    size_t off = 0;
    auto alloc = [&](size_t bytes) -> char* {
        char* p = ws + off;
        off += (bytes + 255) & ~(size_t)255;
        return p;
    };
    int* locoff  = (int*)alloc((size_t)TSTEPS * NRANGE * RNG * 4);
    int* rtot    = (int*)alloc((size_t)TSTEPS * NRANGE * 4);
    int* rbase   = (int*)alloc((size_t)TSTEPS * NRANGE * 4);
    int* rowptr  = (int*)alloc((size_t)TSTEPS * (NNODES + 1) * 4);
    int* csr_src = (int*)alloc((size_t)TSTEPS * ETOT * 4);
    half_t* embh = (half_t*)alloc((size_t)TSTEPS * NNODES * EMB * 2);
    half_t* embl = (half_t*)alloc((size_t)TSTEPS * NNODES * EMB * 2);
    half_t* gW1h = (half_t*)alloc((size_t)2 * HC * EMB * 2);
    half_t* gW2h = (half_t*)alloc((size_t)2 * HC * EMB * 2);
    half_t* lW1h = (half_t*)alloc((size_t)2 * EMB * HC * 2);
    half_t* lW2h = (half_t*)alloc((size_t)2 * EMB * HC * 2);
    half_t* fc1Wh = (half_t*)alloc((size_t)EMB * 2 * EMB * TSTEPS * 2);
    float* wasb = (float*)alloc((size_t)2 * 2 * 4 * 128 * 4);
    float* wadb = (float*)alloc((size_t)2 * 2 * 4 * 128 * 4);
    float* s0src = (float*)alloc((size_t)TSTEPS * 2 * NNODES * 4 * 4);
    float* s0dst = (float*)alloc((size_t)TSTEPS * 2 * NNODES * 4 * 4);
    float* s1src = (float*)alloc((size_t)2 * NNODES * 4 * 4);
    float* s1dst = (float*)alloc((size_t)2 * NNODES * 4 * 4);
    half_t* Hbuf = (half_t*)alloc((size_t)2 * NNODES * HC * 2);
    half_t* Xh   = (half_t*)alloc((size_t)2 * NNODES * EMB * 2);
    half_t* Xl   = (half_t*)alloc((size_t)2 * NNODES * EMB * 2);
    half_t* flath = (half_t*)alloc((size_t)BCLF * (TSTEPS * 2 * EMB) * 2);
    half_t* flatl = (half_t*)alloc((size_t)BCLF * (TSTEPS * 2 * EMB) * 2);
    float* h1buf = (float*)alloc((size_t)BCLF * EMB * 4);

    // conversions
    {
        long n4 = (long)TSTEPS * NNODES * EMB / 4;
        cvt_split_kernel<<<(int)((n4 + 255) / 256), 256, 0, stream>>>(emb, embh, embl, n4);
        long w4 = (long)2 * HC * EMB / 4;
        int wb = (int)((w4 + 255) / 256);
        cvt_h_kernel<<<wb, 256, 0, stream>>>(gat_W1, gW1h, w4);
        cvt_h_kernel<<<wb, 256, 0, stream>>>(gat_W2, gW2h, w4);
        cvt_h_kernel<<<wb, 256, 0, stream>>>(lin_W1, lW1h, w4);
        cvt_h_kernel<<<wb, 256, 0, stream>>>(lin_W2, lW2h, w4);
        long f4 = (long)EMB * 2 * EMB * TSTEPS / 4;
        cvt_h_kernel<<<(int)((f4 + 255) / 256), 256, 0, stream>>>(fc1_W, fc1Wh, f4);
    }
    prep_was_kernel<<<16, 128, 0, stream>>>(gat_W1, gat_W2, gat_as1, gat_as2,
                                            gat_ad1, gat_ad2, wasb, wadb);
    scores0_all_kernel<<<dim3(5000 * TSTEPS, 2), 256, 0, stream>>>(emb, wasb, wadb, s0src, s0dst);

    // CSR build
    rc_count<<<dim3(NRANGE, TSTEPS), 256, 0, stream>>>(edges, locoff, rtot);
    rc_base<<<1, 64, 0, stream>>>(rtot, rbase);
    rc_fill<<<dim3(NRANGE, TSTEPS), 256, 0, stream>>>(edges, locoff, rtot, rbase, rowptr, csr_src);

    for (int t = 0; t < TSTEPS; t++) {
        // ---- layer 0 ----
        const half_t* A0h = embh + (long)t * NNODES * EMB;
        const half_t* A0l = embl + (long)t * NNODES * EMB;
        gemm_as<false, false, false><<<dim3(157, 4, 2), 256, 0, stream>>>(
            A0h, A0l, A0h, A0l, gW1h, gW2h, nullptr, nullptr,
            Hbuf, nullptr, (long)NNODES * HC, NNODES, HC, EMB);
        agg_fused<true><<<dim3(1250, 2), 256, 0, stream>>>(
            Hbuf, s0src + (long)t * 2 * NNODES * 4, s0dst + (long)t * 2 * NNODES * 4,
            rowptr, csr_src, gat_b1, gat_b2, lW1h, lW2h, lin_b1, lin_b2,
            Xh, Xl, wasb + 1024, wadb + 1024, s1src, s1dst, t);
        // ---- layer 1 ----
        gemm_as<false, false, false><<<dim3(157, 4, 2), 256, 0, stream>>>(
            Xh, Xl, Xh + (long)NNODES * EMB, Xl + (long)NNODES * EMB,
            gW1h + (long)HC * EMB, gW2h + (long)HC * EMB, nullptr, nullptr,
            Hbuf, nullptr, (long)NNODES * HC, NNODES, HC, EMB);
        agg_fused<false><<<dim3(1250, 2), 256, 0, stream>>>(
            Hbuf, s1src, s1dst, rowptr, csr_src,
            gat_b1 + HC, gat_b2 + HC, lW1h + (long)EMB * HC, lW2h + (long)EMB * HC,
            lin_b1 + EMB, lin_b2 + EMB,
            Xh, Xl, nullptr, nullptr, nullptr, nullptr, t);
        gather_kernel<<<dim3(BCLF, 2), 64, 0, stream>>>(Xh, Xl, clf, flath, flatl, t);
    }
    // head MLP
    gemm_as<true, true, true><<<dim3(32, 1, 1), 256, 0, stream>>>(
        flath, flatl, flath, flatl, fc1Wh, fc1Wh, fc1_b, fc1_b,
        nullptr, h1buf, 0, BCLF, EMB, TSTEPS * 2 * EMB);
    fc2_kernel<<<BCLF, 64, 0, stream>>>(h1buf, fc2_W, fc2_b, out);
}

// Round 5
// 3651.318 us; speedup vs baseline: 1.7592x; 1.7592x over previous
//
#include <hip/hip_runtime.h>
#include <cstdint>

#define NNODES 20000
#define NEDGES 320000
#define ETOT   340000   // NEDGES + NNODES self loops
#define TSTEPS 10
#define BCLF   4096
#define EMB    128
#define HC     512      // HEADS * EMB
#define NEG_SLOPE 0.2f

typedef _Float16 half_t;
typedef __attribute__((ext_vector_type(8))) _Float16 half8;
typedef __attribute__((ext_vector_type(4))) float floatx4;

// ---------------- conversions ----------------
__global__ void cvt_h_kernel(const float* __restrict__ in, half_t* __restrict__ out, long n4) {
    long i = (long)blockIdx.x * 256 + threadIdx.x;
    if (i >= n4) return;
    float4 v = *(const float4*)&in[i * 4];
    half_t o[4] = {(half_t)v.x, (half_t)v.y, (half_t)v.z, (half_t)v.w};
    *(unsigned long long*)&out[i * 4] = *(unsigned long long*)o;
}

__global__ void cvt_split_kernel(const float* __restrict__ in,
                                 half_t* __restrict__ hi, half_t* __restrict__ lo, long n4) {
    long i = (long)blockIdx.x * 256 + threadIdx.x;
    if (i >= n4) return;
    float4 v = *(const float4*)&in[i * 4];
    half_t h[4], l[4];
    h[0] = (half_t)v.x; l[0] = (half_t)(v.x - (float)h[0]);
    h[1] = (half_t)v.y; l[1] = (half_t)(v.y - (float)h[1]);
    h[2] = (half_t)v.z; l[2] = (half_t)(v.z - (float)h[2]);
    h[3] = (half_t)v.w; l[3] = (half_t)(v.w - (float)h[3]);
    *(unsigned long long*)&hi[i * 4] = *(unsigned long long*)h;
    *(unsigned long long*)&lo[i * 4] = *(unsigned long long*)l;
}

// ---------------- CSR build (R1-proven: count / scan / fill) ----------------
__global__ void count_kernel(const int* __restrict__ edges, int* __restrict__ counts) {
    int e = blockIdx.x * 256 + threadIdx.x;
    int g = blockIdx.y;
    if (e >= ETOT) return;
    int d = (e < NEDGES) ? edges[(g * 2 + 1) * NEDGES + e] : (e - NEDGES);
    atomicAdd(&counts[g * NNODES + d], 1);
}

__global__ void scan_kernel(const int* __restrict__ counts, int* __restrict__ rowptr,
                            int* __restrict__ cursor) {
    int g = blockIdx.x;
    __shared__ int buf[256];
    __shared__ int carry_s;
    if (threadIdx.x == 0) carry_s = 0;
    __syncthreads();
    const int* c = counts + g * NNODES;
    int* rp = rowptr + g * (NNODES + 1);
    int* cu = cursor + g * NNODES;
    for (int base = 0; base < NNODES; base += 256) {
        int i = base + threadIdx.x;
        int v = (i < NNODES) ? c[i] : 0;
        buf[threadIdx.x] = v;
        __syncthreads();
        for (int off = 1; off < 256; off <<= 1) {
            int t = (threadIdx.x >= off) ? buf[threadIdx.x - off] : 0;
            __syncthreads();
            buf[threadIdx.x] += t;
            __syncthreads();
        }
        int excl = carry_s + buf[threadIdx.x] - v;
        if (i < NNODES) { rp[i] = excl; cu[i] = excl; }
        int tot = buf[255];
        __syncthreads();
        if (threadIdx.x == 0) carry_s += tot;
        __syncthreads();
    }
    if (threadIdx.x == 0) rp[NNODES] = carry_s;
}

__global__ void fill_kernel(const int* __restrict__ edges, int* __restrict__ cursor,
                            int* __restrict__ csr_src) {
    int e = blockIdx.x * 256 + threadIdx.x;
    int g = blockIdx.y;
    if (e >= ETOT) return;
    int s, d;
    if (e < NEDGES) { s = edges[(g * 2) * NEDGES + e]; d = edges[(g * 2 + 1) * NEDGES + e]; }
    else           { s = e - NEDGES; d = s; }
    int pos = atomicAdd(&cursor[g * NNODES + d], 1);
    csr_src[(long)g * ETOT + pos] = s;
}

// ---------------- precompute was/wad: was[l][z][h][k] = sum_c W[h*128+c][k]*as[h][c] ----------------
__global__ void prep_was_kernel(const float* __restrict__ W1, const float* __restrict__ W2,
                                const float* __restrict__ as1, const float* __restrict__ as2,
                                const float* __restrict__ ad1, const float* __restrict__ ad2,
                                float* __restrict__ was, float* __restrict__ wad) {
    int b = blockIdx.x;            // l*8 + z*4 + h
    int l = b >> 3, z = (b >> 2) & 1, h = b & 3;
    int k = threadIdx.x;           // 128
    const float* W  = z ? W2 : W1;
    const float* av = z ? as2 : as1;
    const float* dv = z ? ad2 : ad1;
    float s = 0.f, d = 0.f;
    for (int c = 0; c < 128; c++) {
        float w = W[(long)l * HC * EMB + (h * 128 + c) * 128 + k];
        s = fmaf(w, av[(l * 4 + h) * 128 + c], s);
        d = fmaf(w, dv[(l * 4 + h) * 128 + c], d);
    }
    long idx = ((l * 2 + z) * 4 + h) * 128 + k;
    was[idx] = s;
    wad[idx] = d;
}

// ---------------- precompute fused projection B[inst][k][h*128+c] = sum_c' gW[h*128+c',c]*lW[k,h*128+c'] ----------------
__global__ void prep_M_kernel(const float* __restrict__ gW1, const float* __restrict__ gW2,
                              const float* __restrict__ lW1, const float* __restrict__ lW2,
                              half_t* __restrict__ Mh, half_t* __restrict__ Ml) {
    int k = blockIdx.x;            // 0..127 (output channel)
    int inst = blockIdx.y;         // l*2 + z
    int l = inst >> 1, z = inst & 1;
    int c = threadIdx.x;           // 0..127
    const float* gW = (z ? gW2 : gW1) + (long)l * HC * EMB;   // [512][128]
    const float* lW = (z ? lW2 : lW1) + (long)l * EMB * HC;   // [128][512]
    float acc[4] = {0.f, 0.f, 0.f, 0.f};
    for (int cp = 0; cp < 128; cp++) {
#pragma unroll
        for (int h = 0; h < 4; h++) {
            float lw = lW[(long)k * 512 + h * 128 + cp];      // broadcast
            float gw = gW[(long)(h * 128 + cp) * 128 + c];    // coalesced over c
            acc[h] = fmaf(lw, gw, acc[h]);
        }
    }
#pragma unroll
    for (int h = 0; h < 4; h++) {
        long o = ((long)inst * 128 + k) * 512 + h * 128 + c;
        half_t hi = (half_t)acc[h];
        Mh[o] = hi;
        Ml[o] = (half_t)(acc[h] - (float)hi);
    }
}

// cb[inst][k] = sum_j lW[k,j]*gb[j] + lb[k]
__global__ void prep_cb_kernel(const float* __restrict__ lW1, const float* __restrict__ lW2,
                               const float* __restrict__ gb1_, const float* __restrict__ gb2_,
                               const float* __restrict__ lb1_, const float* __restrict__ lb2_,
                               float* __restrict__ cb) {
    int inst = blockIdx.x;
    int l = inst >> 1, z = inst & 1;
    int k = threadIdx.x;
    const float* lW = (z ? lW2 : lW1) + (long)l * EMB * HC;
    const float* gb = (z ? gb2_ : gb1_) + l * HC;
    const float* lb = (z ? lb2_ : lb1_) + l * EMB;
    float a = lb[k];
    for (int j = 0; j < 512; j++) a = fmaf(lW[(long)k * 512 + j], gb[j], a);
    cb[inst * 128 + k] = a;
}

// ---------------- layer-0 scores for ALL timesteps, from fp32 emb ----------------
__global__ __launch_bounds__(256) void scores0_all_kernel(
    const float* __restrict__ emb,
    const float* __restrict__ was0, const float* __restrict__ wad0,   // [z][4][128]
    float* __restrict__ s0src, float* __restrict__ s0dst) {           // [t][z][N][4]
    int z = blockIdx.y;
    int t = blockIdx.x / 5000;
    int nb = blockIdx.x % 5000;
    int n = nb * 4 + (threadIdx.x >> 6);
    int lane = threadIdx.x & 63;
    const float* xr = emb + ((long)t * NNODES + n) * 128;
    float x0 = xr[lane], x1 = xr[64 + lane];
    const float* wz = was0 + z * 512;
    const float* dz = wad0 + z * 512;
    float ps[4], pd[4];
#pragma unroll
    for (int h = 0; h < 4; h++) {
        ps[h] = x0 * wz[h * 128 + lane] + x1 * wz[h * 128 + 64 + lane];
        pd[h] = x0 * dz[h * 128 + lane] + x1 * dz[h * 128 + 64 + lane];
    }
    for (int off = 32; off; off >>= 1) {
#pragma unroll
        for (int h = 0; h < 4; h++) {
            ps[h] += __shfl_down(ps[h], off);
            pd[h] += __shfl_down(pd[h], off);
        }
    }
    if (lane == 0) {
        long idx = (((long)t * 2 + z) * NNODES + n) * 4;
#pragma unroll
        for (int h = 0; h < 4; h++) {
            s0src[idx + h] = ps[h];
            s0dst[idx + h] = pd[h];
        }
    }
}

// ---------------- layer-1 scores from split-fp16 X ----------------
__global__ __launch_bounds__(256) void scores_x_kernel(
    const half_t* __restrict__ Xh, const half_t* __restrict__ Xl,    // [z][N][128]
    const float* __restrict__ was, const float* __restrict__ wad,    // [z][4][128]
    float* __restrict__ s_src, float* __restrict__ s_dst) {
    int z = blockIdx.y;
    int n = blockIdx.x * 4 + (threadIdx.x >> 6);
    int lane = threadIdx.x & 63;
    long xb = ((long)z * NNODES + n) * 128;
    float x0 = (float)Xh[xb + lane] + (float)Xl[xb + lane];
    float x1 = (float)Xh[xb + 64 + lane] + (float)Xl[xb + 64 + lane];
    const float* wz = was + z * 512;
    const float* dz = wad + z * 512;
    float ps[4], pd[4];
#pragma unroll
    for (int h = 0; h < 4; h++) {
        ps[h] = x0 * wz[h * 128 + lane] + x1 * wz[h * 128 + 64 + lane];
        pd[h] = x0 * dz[h * 128 + lane] + x1 * dz[h * 128 + 64 + lane];
    }
    for (int off = 32; off; off >>= 1) {
#pragma unroll
        for (int h = 0; h < 4; h++) {
            ps[h] += __shfl_down(ps[h], off);
            pd[h] += __shfl_down(pd[h], off);
        }
    }
    if (lane == 0) {
        long idx = ((long)z * NNODES + n) * 4;
#pragma unroll
        for (int h = 0; h < 4; h++) {
            s_src[idx + h] = ps[h];
            s_dst[idx + h] = pd[h];
        }
    }
}

// ---------------- agg_x: Y[z][n][h*128+c] = (1/den_h) * sum_e exp(leaky(ss_h+sd_h)) * X[src][c] ----------------
// one wave per (z, dst); lane holds channels 2*lane, 2*lane+1; 4 heads in registers
__global__ __launch_bounds__(256) void agg_x_kernel(
    const half_t* __restrict__ X, long xzstride,                     // [z?][N][128] fp16 hi
    const float* __restrict__ s_src, const float* __restrict__ s_dst,// [z][N][4]
    const int* __restrict__ rowptr, const int* __restrict__ csr_src,
    half_t* __restrict__ Yh, half_t* __restrict__ Yl,                // [z][N][512]
    int g) {
    int z = blockIdx.y;
    int n = blockIdx.x * 4 + (threadIdx.x >> 6);
    int lane = threadIdx.x & 63;
    const int* rp = rowptr + g * (NNODES + 1);
    int beg = rp[n], end = rp[n + 1];
    const int* cs = csr_src + (long)g * ETOT;
    float4 sdv = *(const float4*)&s_dst[((long)z * NNODES + n) * 4];
    const half_t* Xz = X + (long)z * xzstride;
    float acc[4][2];
#pragma unroll
    for (int h = 0; h < 4; h++) { acc[h][0] = 0.f; acc[h][1] = 0.f; }
    float den[4] = {0.f, 0.f, 0.f, 0.f};
    for (int j = beg; j < end; j++) {
        int src = cs[j];
        float4 ssv = *(const float4*)&s_src[((long)z * NNODES + src) * 4];  // broadcast
        float L0 = ssv.x + sdv.x, L1 = ssv.y + sdv.y;
        float L2 = ssv.z + sdv.z, L3 = ssv.w + sdv.w;
        L0 = (L0 >= 0.f) ? L0 : NEG_SLOPE * L0;
        L1 = (L1 >= 0.f) ? L1 : NEG_SLOPE * L1;
        L2 = (L2 >= 0.f) ? L2 : NEG_SLOPE * L2;
        L3 = (L3 >= 0.f) ? L3 : NEG_SLOPE * L3;
        float e0 = __expf(L0), e1 = __expf(L1), e2 = __expf(L2), e3 = __expf(L3);
        den[0] += e0; den[1] += e1; den[2] += e2; den[3] += e3;
        union { unsigned int u; half_t hh[2]; } cv;
        cv.u = *(const unsigned int*)&Xz[(long)src * 128 + lane * 2];
        float x0 = (float)cv.hh[0], x1 = (float)cv.hh[1];
        acc[0][0] = fmaf(e0, x0, acc[0][0]); acc[0][1] = fmaf(e0, x1, acc[0][1]);
        acc[1][0] = fmaf(e1, x0, acc[1][0]); acc[1][1] = fmaf(e1, x1, acc[1][1]);
        acc[2][0] = fmaf(e2, x0, acc[2][0]); acc[2][1] = fmaf(e2, x1, acc[2][1]);
        acc[3][0] = fmaf(e3, x0, acc[3][0]); acc[3][1] = fmaf(e3, x1, acc[3][1]);
    }
    long yb = ((long)z * NNODES + n) * 512;
#pragma unroll
    for (int h = 0; h < 4; h++) {
        float inv = 1.0f / den[h];
        float v0 = acc[h][0] * inv, v1 = acc[h][1] * inv;
        union { unsigned int u; half_t hh[2]; } oh, ol;
        oh.hh[0] = (half_t)v0;
        oh.hh[1] = (half_t)v1;
        ol.hh[0] = (half_t)(v0 - (float)oh.hh[0]);
        ol.hh[1] = (half_t)(v1 - (float)oh.hh[1]);
        *(unsigned int*)&Yh[yb + h * 128 + lane * 2] = oh.u;
        *(unsigned int*)&Yl[yb + h * 128 + lane * 2] = ol.u;
    }
}

// ---------------- split-fp16 MFMA GEMM (both A and B split, 3 MFMAs): C = relu(A@B^T + bias) ----------------
// Tile 128x128, BK=32, 4 waves, 4x4 of 16x16x32 MFMAs. blockIdx.z = branch. N==128 per our uses.
template <bool F32OUT>
__global__ __launch_bounds__(256) void gemm_3m(
    const half_t* __restrict__ A0h, const half_t* __restrict__ A0l,
    const half_t* __restrict__ A1h, const half_t* __restrict__ A1l,
    const half_t* __restrict__ B0h, const half_t* __restrict__ B0l,
    const half_t* __restrict__ B1h, const half_t* __restrict__ B1l,
    const float* __restrict__ bias0, const float* __restrict__ bias1,
    half_t* __restrict__ Ch, half_t* __restrict__ Cl, float* __restrict__ Cf,
    long cStride, int M, int N, int K) {
    const int z = blockIdx.z;
    const half_t* __restrict__ Ah = z ? A1h : A0h;
    const half_t* __restrict__ Al = z ? A1l : A0l;
    const half_t* __restrict__ Bh = z ? B1h : B0h;
    const half_t* __restrict__ Bl = z ? B1l : B0l;
    const float* __restrict__ bias = z ? bias1 : bias0;

    __shared__ half_t Ash[4 * 128 * 8];
    __shared__ half_t Asl[4 * 128 * 8];
    __shared__ half_t Bsh[4 * 128 * 8];
    __shared__ half_t Bsl[4 * 128 * 8];

    const int tid = threadIdx.x;
    const int row0 = blockIdx.x * 128;
    const int col0 = blockIdx.y * 128;
    const int wave = tid >> 6;
    const int lane = tid & 63;
    const int wm = (wave >> 1) * 64;
    const int wn = (wave & 1) * 64;
    const int chunk = lane >> 4;
    const int l16 = lane & 15;

    floatx4 acc[4][4];
#pragma unroll
    for (int i = 0; i < 4; i++)
#pragma unroll
        for (int j = 0; j < 4; j++) acc[i][j] = (floatx4)0.0f;

    for (int k0 = 0; k0 < K; k0 += 32) {
        __syncthreads();
#pragma unroll
        for (int p = 0; p < 2; p++) {
            int idx = p * 256 + tid;
            int r = idx >> 2, kc = idx & 3;
            int arow = row0 + r;
            half8 vah, val;
            if (arow < M) {
                vah = *(const half8*)&Ah[(long)arow * K + k0 + kc * 8];
                val = *(const half8*)&Al[(long)arow * K + k0 + kc * 8];
            } else {
#pragma unroll
                for (int q = 0; q < 8; q++) { vah[q] = (half_t)0.f; val[q] = (half_t)0.f; }
            }
            *(half8*)&Ash[(kc * 128 + r) * 8] = vah;
            *(half8*)&Asl[(kc * 128 + r) * 8] = val;
            long boff = (long)(col0 + r) * K + k0 + kc * 8;
            *(half8*)&Bsh[(kc * 128 + r) * 8] = *(const half8*)&Bh[boff];
            *(half8*)&Bsl[(kc * 128 + r) * 8] = *(const half8*)&Bl[boff];
        }
        __syncthreads();
        half8 afh[4], afl[4], bfh[4], bfl[4];
#pragma unroll
        for (int mi = 0; mi < 4; mi++) {
            int o = (chunk * 128 + wm + mi * 16 + l16) * 8;
            afh[mi] = *(const half8*)&Ash[o];
            afl[mi] = *(const half8*)&Asl[o];
        }
#pragma unroll
        for (int ni = 0; ni < 4; ni++) {
            int o = (chunk * 128 + wn + ni * 16 + l16) * 8;
            bfh[ni] = *(const half8*)&Bsh[o];
            bfl[ni] = *(const half8*)&Bsl[o];
        }
#pragma unroll
        for (int mi = 0; mi < 4; mi++)
#pragma unroll
            for (int ni = 0; ni < 4; ni++) {
                acc[mi][ni] = __builtin_amdgcn_mfma_f32_16x16x32_f16(
                    afh[mi], bfh[ni], acc[mi][ni], 0, 0, 0);
                acc[mi][ni] = __builtin_amdgcn_mfma_f32_16x16x32_f16(
                    afh[mi], bfl[ni], acc[mi][ni], 0, 0, 0);
                acc[mi][ni] = __builtin_amdgcn_mfma_f32_16x16x32_f16(
                    afl[mi], bfh[ni], acc[mi][ni], 0, 0, 0);
            }
    }

    // C/D layout: col = lane&15, row = (lane>>4)*4 + reg
    const int r4 = (lane >> 4) * 4;
#pragma unroll
    for (int mi = 0; mi < 4; mi++) {
#pragma unroll
        for (int reg = 0; reg < 4; reg++) {
            int row = row0 + wm + mi * 16 + r4 + reg;
            if (row >= M) continue;
#pragma unroll
            for (int ni = 0; ni < 4; ni++) {
                int col = col0 + wn + ni * 16 + l16;
                float v = fmaxf(acc[mi][ni][reg] + bias[col], 0.f);
                long o = (long)z * cStride + (long)row * N + col;
                if (F32OUT) {
                    Cf[o] = v;
                } else {
                    half_t hi = (half_t)v;
                    Ch[o] = hi;
                    Cl[o] = (half_t)(v - (float)hi);
                }
            }
        }
    }
}

// ---------------- gather clf_nodes into flat MLP input (reversed timesteps) ----------------
__global__ void gather_kernel(const half_t* __restrict__ Xh, const half_t* __restrict__ Xl,
                              const int* __restrict__ clf,
                              half_t* __restrict__ flath, half_t* __restrict__ flatl, int t) {
    int b = blockIdx.x;
    int z = blockIdx.y;
    int j = threadIdx.x;  // 64 dwords = 128 halves
    int node = clf[b];
    long dst = (long)b * (TSTEPS * 2 * EMB) + (TSTEPS - 1 - t) * (2 * EMB) + z * EMB;
    long src = ((long)z * NNODES + node) * EMB;
    ((unsigned int*)&flath[dst])[j] = ((const unsigned int*)&Xh[src])[j];
    ((unsigned int*)&flatl[dst])[j] = ((const unsigned int*)&Xl[src])[j];
}

// ---------------- fc2: [B,128] @ [2,128]^T + bias, relu, fp32 out ----------------
__global__ void fc2_kernel(const float* __restrict__ h1, const float* __restrict__ W,
                           const float* __restrict__ bias, float* __restrict__ out) {
    int row = blockIdx.x;
    int lane = threadIdx.x;  // 64
    float x0 = h1[(long)row * 128 + lane];
    float x1 = h1[(long)row * 128 + 64 + lane];
    float p0 = x0 * W[lane] + x1 * W[64 + lane];
    float p1 = x0 * W[128 + lane] + x1 * W[192 + lane];
    for (int off = 32; off; off >>= 1) {
        p0 += __shfl_down(p0, off);
        p1 += __shfl_down(p1, off);
    }
    if (lane == 0) {
        out[row * 2 + 0] = fmaxf(p0 + bias[0], 0.f);
        out[row * 2 + 1] = fmaxf(p1 + bias[1], 0.f);
    }
}

extern "C" void kernel_launch(void* const* d_in, const int* in_sizes, int n_in,
                              void* d_out, int out_size, void* d_ws, size_t ws_size,
                              hipStream_t stream) {
    const float* emb     = (const float*)d_in[0];
    const int*   edges   = (const int*)d_in[1];
    const int*   clf     = (const int*)d_in[5];
    const float* gat_W1  = (const float*)d_in[6];
    const float* gat_as1 = (const float*)d_in[7];
    const float* gat_ad1 = (const float*)d_in[8];
    const float* gat_b1  = (const float*)d_in[9];
    const float* lin_W1  = (const float*)d_in[10];
    const float* lin_b1  = (const float*)d_in[11];
    const float* gat_W2  = (const float*)d_in[12];
    const float* gat_as2 = (const float*)d_in[13];
    const float* gat_ad2 = (const float*)d_in[14];
    const float* gat_b2  = (const float*)d_in[15];
    const float* lin_W2  = (const float*)d_in[16];
    const float* lin_b2  = (const float*)d_in[17];
    const float* fc1_W   = (const float*)d_in[18];
    const float* fc1_b   = (const float*)d_in[19];
    const float* fc2_W   = (const float*)d_in[20];
    const float* fc2_b   = (const float*)d_in[21];
    float* out = (float*)d_out;

    char* ws = (char*)d_ws;
    size_t off = 0;
    auto alloc = [&](size_t bytes) -> char* {
        char* p = ws + off;
        off += (bytes + 255) & ~(size_t)255;
        return p;
    };
    int* counts  = (int*)alloc((size_t)TSTEPS * NNODES * 4);
    int* cursor  = (int*)alloc((size_t)TSTEPS * NNODES * 4);
    int* rowptr  = (int*)alloc((size_t)TSTEPS * (NNODES + 1) * 4);
    int* csr_src = (int*)alloc((size_t)TSTEPS * ETOT * 4);
    half_t* embh = (half_t*)alloc((size_t)TSTEPS * NNODES * EMB * 2);
    half_t* Mh   = (half_t*)alloc((size_t)4 * EMB * HC * 2);
    half_t* Ml   = (half_t*)alloc((size_t)4 * EMB * HC * 2);
    float*  cb   = (float*)alloc((size_t)4 * EMB * 4);
    half_t* fc1Wh = (half_t*)alloc((size_t)EMB * 2 * EMB * TSTEPS * 2);
    half_t* fc1Wl = (half_t*)alloc((size_t)EMB * 2 * EMB * TSTEPS * 2);
    float* wasb = (float*)alloc((size_t)2 * 2 * 4 * 128 * 4);
    float* wadb = (float*)alloc((size_t)2 * 2 * 4 * 128 * 4);
    float* s0src = (float*)alloc((size_t)TSTEPS * 2 * NNODES * 4 * 4);
    float* s0dst = (float*)alloc((size_t)TSTEPS * 2 * NNODES * 4 * 4);
    float* s1src = (float*)alloc((size_t)2 * NNODES * 4 * 4);
    float* s1dst = (float*)alloc((size_t)2 * NNODES * 4 * 4);
    half_t* Yh   = (half_t*)alloc((size_t)2 * NNODES * HC * 2);
    half_t* Yl   = (half_t*)alloc((size_t)2 * NNODES * HC * 2);
    half_t* Xh   = (half_t*)alloc((size_t)2 * NNODES * EMB * 2);
    half_t* Xl   = (half_t*)alloc((size_t)2 * NNODES * EMB * 2);
    half_t* flath = (half_t*)alloc((size_t)BCLF * (TSTEPS * 2 * EMB) * 2);
    half_t* flatl = (half_t*)alloc((size_t)BCLF * (TSTEPS * 2 * EMB) * 2);
    float* h1buf = (float*)alloc((size_t)BCLF * EMB * 4);

    const int eblocks = (ETOT + 255) / 256;  // 1329

    // conversions + fused-weight precompute
    {
        long n4 = (long)TSTEPS * NNODES * EMB / 4;
        cvt_h_kernel<<<(int)((n4 + 255) / 256), 256, 0, stream>>>(emb, embh, n4);
        long f4 = (long)EMB * 2 * EMB * TSTEPS / 4;
        cvt_split_kernel<<<(int)((f4 + 255) / 256), 256, 0, stream>>>(fc1_W, fc1Wh, fc1Wl, f4);
    }
    prep_was_kernel<<<16, 128, 0, stream>>>(gat_W1, gat_W2, gat_as1, gat_as2,
                                            gat_ad1, gat_ad2, wasb, wadb);
    prep_M_kernel<<<dim3(128, 4), 128, 0, stream>>>(gat_W1, gat_W2, lin_W1, lin_W2, Mh, Ml);
    prep_cb_kernel<<<4, 128, 0, stream>>>(lin_W1, lin_W2, gat_b1, gat_b2, lin_b1, lin_b2, cb);
    scores0_all_kernel<<<dim3(5000 * TSTEPS, 2), 256, 0, stream>>>(emb, wasb, wadb, s0src, s0dst);

    // CSR build
    hipMemsetAsync(counts, 0, (size_t)TSTEPS * NNODES * 4, stream);
    count_kernel<<<dim3(eblocks, TSTEPS), 256, 0, stream>>>(edges, counts);
    scan_kernel<<<TSTEPS, 256, 0, stream>>>(counts, rowptr, cursor);
    fill_kernel<<<dim3(eblocks, TSTEPS), 256, 0, stream>>>(edges, cursor, csr_src);

    for (int t = 0; t < TSTEPS; t++) {
        // ---- layer 0: aggregate emb (shared across z), project via M[0..1] ----
        agg_x_kernel<<<dim3(5000, 2), 256, 0, stream>>>(
            embh + (long)t * NNODES * EMB, 0,
            s0src + (long)t * 2 * NNODES * 4, s0dst + (long)t * 2 * NNODES * 4,
            rowptr, csr_src, Yh, Yl, t);
        gemm_3m<false><<<dim3(157, 1, 2), 256, 0, stream>>>(
            Yh, Yl, Yh + (long)NNODES * HC, Yl + (long)NNODES * HC,
            Mh, Ml, Mh + (long)EMB * HC, Ml + (long)EMB * HC,
            cb, cb + EMB,
            Xh, Xl, nullptr, (long)NNODES * EMB, NNODES, EMB, HC);
        scores_x_kernel<<<dim3(5000, 2), 256, 0, stream>>>(
            Xh, Xl, wasb + 1024, wadb + 1024, s1src, s1dst);
        // ---- layer 1 ----
        agg_x_kernel<<<dim3(5000, 2), 256, 0, stream>>>(
            Xh, (long)NNODES * EMB, s1src, s1dst, rowptr, csr_src, Yh, Yl, t);
        gemm_3m<false><<<dim3(157, 1, 2), 256, 0, stream>>>(
            Yh, Yl, Yh + (long)NNODES * HC, Yl + (long)NNODES * HC,
            Mh + (long)2 * EMB * HC, Ml + (long)2 * EMB * HC,
            Mh + (long)3 * EMB * HC, Ml + (long)3 * EMB * HC,
            cb + 2 * EMB, cb + 3 * EMB,
            Xh, Xl, nullptr, (long)NNODES * EMB, NNODES, EMB, HC);
        gather_kernel<<<dim3(BCLF, 2), 64, 0, stream>>>(Xh, Xl, clf, flath, flatl, t);
    }
    // head MLP
    gemm_3m<true><<<dim3(32, 1, 1), 256, 0, stream>>>(
        flath, flatl, flath, flatl, fc1Wh, fc1Wl, fc1Wh, fc1Wl,
        fc1_b, fc1_b, nullptr, nullptr, h1buf, 0, BCLF, EMB, TSTEPS * 2 * EMB);
    fc2_kernel<<<BCLF, 64, 0, stream>>>(h1buf, fc2_W, fc2_b, out);
}

// Round 6
// 3247.893 us; speedup vs baseline: 1.9778x; 1.1242x over previous
//
#include <hip/hip_runtime.h>
#include <cstdint>

#define NNODES 20000
#define NEDGES 320000
#define ETOT   340000   // NEDGES + NNODES self loops
#define TSTEPS 10
#define BCLF   4096
#define EMB    128
#define HC     512      // HEADS * EMB
#define NEG_SLOPE 0.2f

typedef _Float16 half_t;
typedef __attribute__((ext_vector_type(8))) _Float16 half8;
typedef __attribute__((ext_vector_type(4))) float floatx4;

// ---------------- conversions ----------------
__global__ void cvt_split_kernel(const float* __restrict__ in,
                                 half_t* __restrict__ hi, half_t* __restrict__ lo, long n4) {
    long i = (long)blockIdx.x * 256 + threadIdx.x;
    if (i >= n4) return;
    float4 v = *(const float4*)&in[i * 4];
    half_t h[4], l[4];
    h[0] = (half_t)v.x; l[0] = (half_t)(v.x - (float)h[0]);
    h[1] = (half_t)v.y; l[1] = (half_t)(v.y - (float)h[1]);
    h[2] = (half_t)v.z; l[2] = (half_t)(v.z - (float)h[2]);
    h[3] = (half_t)v.w; l[3] = (half_t)(v.w - (float)h[3]);
    *(unsigned long long*)&hi[i * 4] = *(unsigned long long*)h;
    *(unsigned long long*)&lo[i * 4] = *(unsigned long long*)l;
}

// ---------------- CSR build (R1-proven: count / scan / fill) ----------------
__global__ void count_kernel(const int* __restrict__ edges, int* __restrict__ counts) {
    int e = blockIdx.x * 256 + threadIdx.x;
    int g = blockIdx.y;
    if (e >= ETOT) return;
    int d = (e < NEDGES) ? edges[(g * 2 + 1) * NEDGES + e] : (e - NEDGES);
    atomicAdd(&counts[g * NNODES + d], 1);
}

__global__ void scan_kernel(const int* __restrict__ counts, int* __restrict__ rowptr,
                            int* __restrict__ cursor) {
    int g = blockIdx.x;
    __shared__ int buf[256];
    __shared__ int carry_s;
    if (threadIdx.x == 0) carry_s = 0;
    __syncthreads();
    const int* c = counts + g * NNODES;
    int* rp = rowptr + g * (NNODES + 1);
    int* cu = cursor + g * NNODES;
    for (int base = 0; base < NNODES; base += 256) {
        int i = base + threadIdx.x;
        int v = (i < NNODES) ? c[i] : 0;
        buf[threadIdx.x] = v;
        __syncthreads();
        for (int off = 1; off < 256; off <<= 1) {
            int t = (threadIdx.x >= off) ? buf[threadIdx.x - off] : 0;
            __syncthreads();
            buf[threadIdx.x] += t;
            __syncthreads();
        }
        int excl = carry_s + buf[threadIdx.x] - v;
        if (i < NNODES) { rp[i] = excl; cu[i] = excl; }
        int tot = buf[255];
        __syncthreads();
        if (threadIdx.x == 0) carry_s += tot;
        __syncthreads();
    }
    if (threadIdx.x == 0) rp[NNODES] = carry_s;
}

__global__ void fill_kernel(const int* __restrict__ edges, int* __restrict__ cursor,
                            int* __restrict__ csr_src) {
    int e = blockIdx.x * 256 + threadIdx.x;
    int g = blockIdx.y;
    if (e >= ETOT) return;
    int s, d;
    if (e < NEDGES) { s = edges[(g * 2) * NEDGES + e]; d = edges[(g * 2 + 1) * NEDGES + e]; }
    else           { s = e - NEDGES; d = s; }
    int pos = atomicAdd(&cursor[g * NNODES + d], 1);
    csr_src[(long)g * ETOT + pos] = s;
}

// ---------------- precompute was/wad: was[l][z][h][k] = sum_c W[h*128+c][k]*as[h][c] ----------------
__global__ void prep_was_kernel(const float* __restrict__ W1, const float* __restrict__ W2,
                                const float* __restrict__ as1, const float* __restrict__ as2,
                                const float* __restrict__ ad1, const float* __restrict__ ad2,
                                float* __restrict__ was, float* __restrict__ wad) {
    int b = blockIdx.x;            // l*8 + z*4 + h
    int l = b >> 3, z = (b >> 2) & 1, h = b & 3;
    int k = threadIdx.x;           // 128
    const float* W  = z ? W2 : W1;
    const float* av = z ? as2 : as1;
    const float* dv = z ? ad2 : ad1;
    float s = 0.f, d = 0.f;
    for (int c = 0; c < 128; c++) {
        float w = W[(long)l * HC * EMB + (h * 128 + c) * 128 + k];
        s = fmaf(w, av[(l * 4 + h) * 128 + c], s);
        d = fmaf(w, dv[(l * 4 + h) * 128 + c], d);
    }
    long idx = ((l * 2 + z) * 4 + h) * 128 + k;
    was[idx] = s;
    wad[idx] = d;
}

// ---------------- pack score-weight matrices for MFMA (split fp16) ----------------
// WS0 [16][128]: rows 0-7 = z0 (0-3 src heads, 4-7 dst heads), 8-15 = z1 (layer 0)
// WS1 [z][16][128]: rows 0-7 = src/dst heads for layer 1, rows 8-15 = zero pad
__global__ void pack_ws_kernel(const float* __restrict__ wasb, const float* __restrict__ wadb,
                               half_t* __restrict__ WS0h, half_t* __restrict__ WS0l,
                               half_t* __restrict__ WS1h, half_t* __restrict__ WS1l) {
    int b = blockIdx.x;   // 0..47
    int k = threadIdx.x;  // 128
    if (b < 16) {
        int z = b >> 3, d = (b >> 2) & 1, h = b & 3;
        const float* src = d ? wadb : wasb;
        float v = src[((long)z * 4 + h) * 128 + k];       // layer0 inst = z
        half_t hi = (half_t)v;
        WS0h[b * 128 + k] = hi;
        WS0l[b * 128 + k] = (half_t)(v - (float)hi);
    } else {
        int b2 = b - 16;
        int z = b2 >> 4, r = b2 & 15;
        float v = 0.f;
        if (r < 8) {
            int d = r >> 2, h = r & 3;
            const float* src = d ? wadb : wasb;
            v = src[((long)(2 + z) * 4 + h) * 128 + k];   // layer1 inst = 2+z
        }
        half_t hi = (half_t)v;
        WS1h[(z * 16 + r) * 128 + k] = hi;
        WS1l[(z * 16 + r) * 128 + k] = (half_t)(v - (float)hi);
    }
}

// ---------------- precompute fused projection M[inst][k][h*128+c] ----------------
__global__ void prep_M_kernel(const float* __restrict__ gW1, const float* __restrict__ gW2,
                              const float* __restrict__ lW1, const float* __restrict__ lW2,
                              half_t* __restrict__ Mh, half_t* __restrict__ Ml) {
    int k = blockIdx.x;            // 0..127 (output channel)
    int inst = blockIdx.y;         // l*2 + z
    int l = inst >> 1, z = inst & 1;
    int c = threadIdx.x;           // 0..127
    const float* gW = (z ? gW2 : gW1) + (long)l * HC * EMB;   // [512][128]
    const float* lW = (z ? lW2 : lW1) + (long)l * EMB * HC;   // [128][512]
    float acc[4] = {0.f, 0.f, 0.f, 0.f};
    for (int cp = 0; cp < 128; cp++) {
#pragma unroll
        for (int h = 0; h < 4; h++) {
            float lw = lW[(long)k * 512 + h * 128 + cp];
            float gw = gW[(long)(h * 128 + cp) * 128 + c];
            acc[h] = fmaf(lw, gw, acc[h]);
        }
    }
#pragma unroll
    for (int h = 0; h < 4; h++) {
        long o = ((long)inst * 128 + k) * 512 + h * 128 + c;
        half_t hi = (half_t)acc[h];
        Mh[o] = hi;
        Ml[o] = (half_t)(acc[h] - (float)hi);
    }
}

// cb[inst][k] = sum_j lW[k,j]*gb[j] + lb[k]
__global__ void prep_cb_kernel(const float* __restrict__ lW1, const float* __restrict__ lW2,
                               const float* __restrict__ gb1_, const float* __restrict__ gb2_,
                               const float* __restrict__ lb1_, const float* __restrict__ lb2_,
                               float* __restrict__ cb) {
    int inst = blockIdx.x;
    int l = inst >> 1, z = inst & 1;
    int k = threadIdx.x;
    const float* lW = (z ? lW2 : lW1) + (long)l * EMB * HC;
    const float* gb = (z ? gb2_ : gb1_) + l * HC;
    const float* lb = (z ? lb2_ : lb1_) + l * EMB;
    float a = lb[k];
    for (int j = 0; j < 512; j++) a = fmaf(lW[(long)k * 512 + j], gb[j], a);
    cb[inst * 128 + k] = a;
}

// ---------------- scores via MFMA: out[row][col] = (Ah+Al)[row] . (WSh+WSl)[col] ----------------
// Block = 4 waves x 16 rows; B (16x128) staged in LDS; 4 k-chunks x 3 split MFMAs.
__global__ __launch_bounds__(256) void scores_mm_kernel(
    const half_t* __restrict__ Ah, const half_t* __restrict__ Al, long aYs,
    const half_t* __restrict__ WSh, const half_t* __restrict__ WSl, long wYs,
    float* __restrict__ out, long oYs, int M, int OS, int CMAX) {
    int z = blockIdx.y;
    Ah += (long)z * aYs; Al += (long)z * aYs;
    WSh += (long)z * wYs; WSl += (long)z * wYs;
    out += (long)z * oYs;
    __shared__ half_t Bh[16 * 128];
    __shared__ half_t Bl[16 * 128];
    int tid = threadIdx.x;
    *(half8*)&Bh[tid * 8] = *(const half8*)&WSh[tid * 8];
    *(half8*)&Bl[tid * 8] = *(const half8*)&WSl[tid * 8];
    __syncthreads();
    int wave = tid >> 6, lane = tid & 63;
    int l16 = lane & 15, chunk = lane >> 4;
    int r0 = blockIdx.x * 64 + wave * 16;
    int rowc = r0 + l16; if (rowc > M - 1) rowc = M - 1;
    floatx4 acc = (floatx4)0.f;
#pragma unroll
    for (int ko = 0; ko < 128; ko += 32) {
        half8 ah = *(const half8*)&Ah[(long)rowc * 128 + ko + chunk * 8];
        half8 al = *(const half8*)&Al[(long)rowc * 128 + ko + chunk * 8];
        half8 bh = *(const half8*)&Bh[l16 * 128 + ko + chunk * 8];
        half8 bl = *(const half8*)&Bl[l16 * 128 + ko + chunk * 8];
        acc = __builtin_amdgcn_mfma_f32_16x16x32_f16(ah, bh, acc, 0, 0, 0);
        acc = __builtin_amdgcn_mfma_f32_16x16x32_f16(ah, bl, acc, 0, 0, 0);
        acc = __builtin_amdgcn_mfma_f32_16x16x32_f16(al, bh, acc, 0, 0, 0);
    }
#pragma unroll
    for (int reg = 0; reg < 4; reg++) {
        int rr = r0 + chunk * 4 + reg;
        if (rr < M && l16 < CMAX) out[(long)rr * OS + l16] = acc[reg];
    }
}

// ---------------- agg_x: head-mapped lanes. Y[z][n][h*128+c] = (1/den_h) sum_e w_e,h * X[src][c] ----
// lane: h = lane>>4 (head), cg = lane&15 (channel group of 8). One wave per (z, dst).
// ss layout: ss[node*sstride + {0..3 src heads | 4..7 dst heads}] after ss += z*szoff.
__global__ __launch_bounds__(256) void agg_x_kernel(
    const half_t* __restrict__ X, long xzstride,
    const float* __restrict__ ss, int sstride, long szoff,
    const int* __restrict__ rowptr, const int* __restrict__ csr_src,
    half_t* __restrict__ Yh, half_t* __restrict__ Yl, int g) {
    int z = blockIdx.y;
    int n = blockIdx.x * 4 + (threadIdx.x >> 6);
    int lane = threadIdx.x & 63;
    int h = lane >> 4, cg = lane & 15;
    const int* rp = rowptr + g * (NNODES + 1);
    int beg = rp[n], end = rp[n + 1];
    const int* cs = csr_src + (long)g * ETOT;
    const half_t* Xz = X + (long)z * xzstride;
    const float* sz = ss + (long)z * szoff;
    float sd = sz[(long)n * sstride + 4 + h];
    float acc[8];
#pragma unroll
    for (int c = 0; c < 8; c++) acc[c] = 0.f;
    float den = 0.f;
    for (int j = beg; j < end; j++) {
        int src = cs[j];
        float sv = sz[(long)src * sstride + h];
        float L = sv + sd;
        L = (L >= 0.f) ? L : NEG_SLOPE * L;
        float w = __expf(L);
        den += w;
        half8 x = *(const half8*)&Xz[(long)src * 128 + cg * 8];
#pragma unroll
        for (int c = 0; c < 8; c++) acc[c] = fmaf(w, (float)x[c], acc[c]);
    }
    float inv = 1.0f / den;
    half8 oh, ol;
#pragma unroll
    for (int c = 0; c < 8; c++) {
        float v = acc[c] * inv;
        half_t hi = (half_t)v;
        oh[c] = hi;
        ol[c] = (half_t)(v - (float)hi);
    }
    long yb = ((long)z * NNODES + n) * 512 + h * 128 + cg * 8;
    *(half8*)&Yh[yb] = oh;
    *(half8*)&Yl[yb] = ol;
}

// ---------------- split-fp16 MFMA GEMM (A and B split, 3 MFMAs): C = relu(A@B^T + bias) ----------------
template <bool F32OUT>
__global__ __launch_bounds__(256) void gemm_3m(
    const half_t* __restrict__ A0h, const half_t* __restrict__ A0l,
    const half_t* __restrict__ A1h, const half_t* __restrict__ A1l,
    const half_t* __restrict__ B0h, const half_t* __restrict__ B0l,
    const half_t* __restrict__ B1h, const half_t* __restrict__ B1l,
    const float* __restrict__ bias0, const float* __restrict__ bias1,
    half_t* __restrict__ Ch, half_t* __restrict__ Cl, float* __restrict__ Cf,
    long cStride, int M, int N, int K) {
    const int z = blockIdx.z;
    const half_t* __restrict__ Ah = z ? A1h : A0h;
    const half_t* __restrict__ Al = z ? A1l : A0l;
    const half_t* __restrict__ Bh = z ? B1h : B0h;
    const half_t* __restrict__ Bl = z ? B1l : B0l;
    const float* __restrict__ bias = z ? bias1 : bias0;

    __shared__ half_t Ash[4 * 128 * 8];
    __shared__ half_t Asl[4 * 128 * 8];
    __shared__ half_t Bsh[4 * 128 * 8];
    __shared__ half_t Bsl[4 * 128 * 8];

    const int tid = threadIdx.x;
    const int row0 = blockIdx.x * 128;
    const int col0 = blockIdx.y * 128;
    const int wave = tid >> 6;
    const int lane = tid & 63;
    const int wm = (wave >> 1) * 64;
    const int wn = (wave & 1) * 64;
    const int chunk = lane >> 4;
    const int l16 = lane & 15;

    floatx4 acc[4][4];
#pragma unroll
    for (int i = 0; i < 4; i++)
#pragma unroll
        for (int j = 0; j < 4; j++) acc[i][j] = (floatx4)0.0f;

    for (int k0 = 0; k0 < K; k0 += 32) {
        __syncthreads();
#pragma unroll
        for (int p = 0; p < 2; p++) {
            int idx = p * 256 + tid;
            int r = idx >> 2, kc = idx & 3;
            int arow = row0 + r;
            half8 vah, val;
            if (arow < M) {
                vah = *(const half8*)&Ah[(long)arow * K + k0 + kc * 8];
                val = *(const half8*)&Al[(long)arow * K + k0 + kc * 8];
            } else {
#pragma unroll
                for (int q = 0; q < 8; q++) { vah[q] = (half_t)0.f; val[q] = (half_t)0.f; }
            }
            *(half8*)&Ash[(kc * 128 + r) * 8] = vah;
            *(half8*)&Asl[(kc * 128 + r) * 8] = val;
            long boff = (long)(col0 + r) * K + k0 + kc * 8;
            *(half8*)&Bsh[(kc * 128 + r) * 8] = *(const half8*)&Bh[boff];
            *(half8*)&Bsl[(kc * 128 + r) * 8] = *(const half8*)&Bl[boff];
        }
        __syncthreads();
        half8 afh[4], afl[4], bfh[4], bfl[4];
#pragma unroll
        for (int mi = 0; mi < 4; mi++) {
            int o = (chunk * 128 + wm + mi * 16 + l16) * 8;
            afh[mi] = *(const half8*)&Ash[o];
            afl[mi] = *(const half8*)&Asl[o];
        }
#pragma unroll
        for (int ni = 0; ni < 4; ni++) {
            int o = (chunk * 128 + wn + ni * 16 + l16) * 8;
            bfh[ni] = *(const half8*)&Bsh[o];
            bfl[ni] = *(const half8*)&Bsl[o];
        }
#pragma unroll
        for (int mi = 0; mi < 4; mi++)
#pragma unroll
            for (int ni = 0; ni < 4; ni++) {
                acc[mi][ni] = __builtin_amdgcn_mfma_f32_16x16x32_f16(
                    afh[mi], bfh[ni], acc[mi][ni], 0, 0, 0);
                acc[mi][ni] = __builtin_amdgcn_mfma_f32_16x16x32_f16(
                    afh[mi], bfl[ni], acc[mi][ni], 0, 0, 0);
                acc[mi][ni] = __builtin_amdgcn_mfma_f32_16x16x32_f16(
                    afl[mi], bfh[ni], acc[mi][ni], 0, 0, 0);
            }
    }

    // C/D layout: col = lane&15, row = (lane>>4)*4 + reg
    const int r4 = (lane >> 4) * 4;
#pragma unroll
    for (int mi = 0; mi < 4; mi++) {
#pragma unroll
        for (int reg = 0; reg < 4; reg++) {
            int row = row0 + wm + mi * 16 + r4 + reg;
            if (row >= M) continue;
#pragma unroll
            for (int ni = 0; ni < 4; ni++) {
                int col = col0 + wn + ni * 16 + l16;
                float v = fmaxf(acc[mi][ni][reg] + bias[col], 0.f);
                long o = (long)z * cStride + (long)row * N + col;
                if (F32OUT) {
                    Cf[o] = v;
                } else {
                    half_t hi = (half_t)v;
                    Ch[o] = hi;
                    Cl[o] = (half_t)(v - (float)hi);
                }
            }
        }
    }
}

// ---------------- gather clf_nodes into flat MLP input (reversed timesteps) ----------------
__global__ void gather_kernel(const half_t* __restrict__ Xh, const half_t* __restrict__ Xl,
                              const int* __restrict__ clf,
                              half_t* __restrict__ flath, half_t* __restrict__ flatl, int t) {
    int b = blockIdx.x;
    int z = blockIdx.y;
    int j = threadIdx.x;  // 64 dwords = 128 halves
    int node = clf[b];
    long dst = (long)b * (TSTEPS * 2 * EMB) + (TSTEPS - 1 - t) * (2 * EMB) + z * EMB;
    long src = ((long)z * NNODES + node) * EMB;
    ((unsigned int*)&flath[dst])[j] = ((const unsigned int*)&Xh[src])[j];
    ((unsigned int*)&flatl[dst])[j] = ((const unsigned int*)&Xl[src])[j];
}

// ---------------- fc2: [B,128] @ [2,128]^T + bias, relu, fp32 out ----------------
__global__ void fc2_kernel(const float* __restrict__ h1, const float* __restrict__ W,
                           const float* __restrict__ bias, float* __restrict__ out) {
    int row = blockIdx.x;
    int lane = threadIdx.x;  // 64
    float x0 = h1[(long)row * 128 + lane];
    float x1 = h1[(long)row * 128 + 64 + lane];
    float p0 = x0 * W[lane] + x1 * W[64 + lane];
    float p1 = x0 * W[128 + lane] + x1 * W[192 + lane];
    for (int off = 32; off; off >>= 1) {
        p0 += __shfl_down(p0, off);
        p1 += __shfl_down(p1, off);
    }
    if (lane == 0) {
        out[row * 2 + 0] = fmaxf(p0 + bias[0], 0.f);
        out[row * 2 + 1] = fmaxf(p1 + bias[1], 0.f);
    }
}

extern "C" void kernel_launch(void* const* d_in, const int* in_sizes, int n_in,
                              void* d_out, int out_size, void* d_ws, size_t ws_size,
                              hipStream_t stream) {
    const float* emb     = (const float*)d_in[0];
    const int*   edges   = (const int*)d_in[1];
    const int*   clf     = (const int*)d_in[5];
    const float* gat_W1  = (const float*)d_in[6];
    const float* gat_as1 = (const float*)d_in[7];
    const float* gat_ad1 = (const float*)d_in[8];
    const float* gat_b1  = (const float*)d_in[9];
    const float* lin_W1  = (const float*)d_in[10];
    const float* lin_b1  = (const float*)d_in[11];
    const float* gat_W2  = (const float*)d_in[12];
    const float* gat_as2 = (const float*)d_in[13];
    const float* gat_ad2 = (const float*)d_in[14];
    const float* gat_b2  = (const float*)d_in[15];
    const float* lin_W2  = (const float*)d_in[16];
    const float* lin_b2  = (const float*)d_in[17];
    const float* fc1_W   = (const float*)d_in[18];
    const float* fc1_b   = (const float*)d_in[19];
    const float* fc2_W   = (const float*)d_in[20];
    const float* fc2_b   = (const float*)d_in[21];
    float* out = (float*)d_out;

    char* ws = (char*)d_ws;
    size_t off = 0;
    auto alloc = [&](size_t bytes) -> char* {
        char* p = ws + off;
        off += (bytes + 255) & ~(size_t)255;
        return p;
    };
    int* counts  = (int*)alloc((size_t)TSTEPS * NNODES * 4);
    int* cursor  = (int*)alloc((size_t)TSTEPS * NNODES * 4);
    int* rowptr  = (int*)alloc((size_t)TSTEPS * (NNODES + 1) * 4);
    int* csr_src = (int*)alloc((size_t)TSTEPS * ETOT * 4);
    half_t* embh = (half_t*)alloc((size_t)TSTEPS * NNODES * EMB * 2);
    half_t* embl = (half_t*)alloc((size_t)TSTEPS * NNODES * EMB * 2);
    half_t* Mh   = (half_t*)alloc((size_t)4 * EMB * HC * 2);
    half_t* Ml   = (half_t*)alloc((size_t)4 * EMB * HC * 2);
    float*  cb   = (float*)alloc((size_t)4 * EMB * 4);
    half_t* fc1Wh = (half_t*)alloc((size_t)EMB * 2 * EMB * TSTEPS * 2);
    half_t* fc1Wl = (half_t*)alloc((size_t)EMB * 2 * EMB * TSTEPS * 2);
    float* wasb = (float*)alloc((size_t)2 * 2 * 4 * 128 * 4);
    float* wadb = (float*)alloc((size_t)2 * 2 * 4 * 128 * 4);
    half_t* WS0h = (half_t*)alloc((size_t)16 * 128 * 2);
    half_t* WS0l = (half_t*)alloc((size_t)16 * 128 * 2);
    half_t* WS1h = (half_t*)alloc((size_t)2 * 16 * 128 * 2);
    half_t* WS1l = (half_t*)alloc((size_t)2 * 16 * 128 * 2);
    float* s0buf = (float*)alloc((size_t)TSTEPS * NNODES * 16 * 4);   // [t][n][16]
    float* s1buf = (float*)alloc((size_t)2 * NNODES * 8 * 4);         // [z][n][8]
    half_t* Yh   = (half_t*)alloc((size_t)2 * NNODES * HC * 2);
    half_t* Yl   = (half_t*)alloc((size_t)2 * NNODES * HC * 2);
    half_t* Xh   = (half_t*)alloc((size_t)2 * NNODES * EMB * 2);
    half_t* Xl   = (half_t*)alloc((size_t)2 * NNODES * EMB * 2);
    half_t* flath = (half_t*)alloc((size_t)BCLF * (TSTEPS * 2 * EMB) * 2);
    half_t* flatl = (half_t*)alloc((size_t)BCLF * (TSTEPS * 2 * EMB) * 2);
    float* h1buf = (float*)alloc((size_t)BCLF * EMB * 4);

    const int eblocks = (ETOT + 255) / 256;  // 1329

    // conversions + fused-weight precompute
    {
        long n4 = (long)TSTEPS * NNODES * EMB / 4;
        cvt_split_kernel<<<(int)((n4 + 255) / 256), 256, 0, stream>>>(emb, embh, embl, n4);
        long f4 = (long)EMB * 2 * EMB * TSTEPS / 4;
        cvt_split_kernel<<<(int)((f4 + 255) / 256), 256, 0, stream>>>(fc1_W, fc1Wh, fc1Wl, f4);
    }
    prep_was_kernel<<<16, 128, 0, stream>>>(gat_W1, gat_W2, gat_as1, gat_as2,
                                            gat_ad1, gat_ad2, wasb, wadb);
    pack_ws_kernel<<<48, 128, 0, stream>>>(wasb, wadb, WS0h, WS0l, WS1h, WS1l);
    prep_M_kernel<<<dim3(128, 4), 128, 0, stream>>>(gat_W1, gat_W2, lin_W1, lin_W2, Mh, Ml);
    prep_cb_kernel<<<4, 128, 0, stream>>>(lin_W1, lin_W2, gat_b1, gat_b2, lin_b1, lin_b2, cb);

    // layer-0 scores for all timesteps, both z, via MFMA: [200000,128]@[128,16]
    scores_mm_kernel<<<dim3(3125, 1), 256, 0, stream>>>(
        embh, embl, 0, WS0h, WS0l, 0, s0buf, 0, TSTEPS * NNODES, 16, 16);

    // CSR build
    hipMemsetAsync(counts, 0, (size_t)TSTEPS * NNODES * 4, stream);
    count_kernel<<<dim3(eblocks, TSTEPS), 256, 0, stream>>>(edges, counts);
    scan_kernel<<<TSTEPS, 256, 0, stream>>>(counts, rowptr, cursor);
    fill_kernel<<<dim3(eblocks, TSTEPS), 256, 0, stream>>>(edges, cursor, csr_src);

    for (int t = 0; t < TSTEPS; t++) {
        // ---- layer 0 ----
        agg_x_kernel<<<dim3(5000, 2), 256, 0, stream>>>(
            embh + (long)t * NNODES * EMB, 0,
            s0buf + (long)t * NNODES * 16, 16, 8,
            rowptr, csr_src, Yh, Yl, t);
        gemm_3m<false><<<dim3(157, 1, 2), 256, 0, stream>>>(
            Yh, Yl, Yh + (long)NNODES * HC, Yl + (long)NNODES * HC,
            Mh, Ml, Mh + (long)EMB * HC, Ml + (long)EMB * HC,
            cb, cb + EMB,
            Xh, Xl, nullptr, (long)NNODES * EMB, NNODES, EMB, HC);
        // layer-1 scores via MFMA
        scores_mm_kernel<<<dim3(313, 2), 256, 0, stream>>>(
            Xh, Xl, (long)NNODES * EMB, WS1h, WS1l, 16 * 128,
            s1buf, (long)NNODES * 8, NNODES, 8, 8);
        // ---- layer 1 ----
        agg_x_kernel<<<dim3(5000, 2), 256, 0, stream>>>(
            Xh, (long)NNODES * EMB, s1buf, 8, (long)NNODES * 8,
            rowptr, csr_src, Yh, Yl, t);
        gemm_3m<false><<<dim3(157, 1, 2), 256, 0, stream>>>(
            Yh, Yl, Yh + (long)NNODES * HC, Yl + (long)NNODES * HC,
            Mh + (long)2 * EMB * HC, Ml + (long)2 * EMB * HC,
            Mh + (long)3 * EMB * HC, Ml + (long)3 * EMB * HC,
            cb + 2 * EMB, cb + 3 * EMB,
            Xh, Xl, nullptr, (long)NNODES * EMB, NNODES, EMB, HC);
        gather_kernel<<<dim3(BCLF, 2), 64, 0, stream>>>(Xh, Xl, clf, flath, flatl, t);
    }
    // head MLP
    gemm_3m<true><<<dim3(32, 1, 1), 256, 0, stream>>>(
        flath, flatl, flath, flatl, fc1Wh, fc1Wl, fc1Wh, fc1Wl,
        fc1_b, fc1_b, nullptr, nullptr, h1buf, 0, BCLF, EMB, TSTEPS * 2 * EMB);
    fc2_kernel<<<BCLF, 64, 0, stream>>>(h1buf, fc2_W, fc2_b, out);
}